// Round 5
// baseline (581.879 us; speedup 1.0000x reference)
//
#include <hip/hip_runtime.h>
#include <hip/hip_bf16.h>
#include <cstdint>

#define NV 3
#define NN 4096
#define HH 256
#define CC 20
#define DYY 300
#define DD 512

typedef __bf16 v8bf  __attribute__((ext_vector_type(8)));
typedef float  v16f  __attribute__((ext_vector_type(16)));

static __device__ __forceinline__ float bf2f(unsigned short u) {
    union { unsigned int i; float f; } c; c.i = ((unsigned int)u) << 16; return c.f;
}

// Stage a 64x64 bf16 tile (8 KB, 512 chunks) via global_load_lds w=16.
// LDS dest linear (HW requirement); XOR swizzle (chunk ^= row&7) applied on
// the GLOBAL source side, matching XOR on ds_read (rule #21).
static __device__ __forceinline__ void stage_tile64(const __bf16* src, int strideElems,
                                                    char* lds, int tid)
{
#pragma unroll
    for (int i = 0; i < 2; ++i) {
        int id = i * 256 + tid;          // 16 B chunk id, 0..511
        int r = id >> 3, c = id & 7;
        const char* g = (const char*)(src + (size_t)r * strideElems)
                        + ((c ^ (r & 7)) << 4);
        __builtin_amdgcn_global_load_lds(
            (const __attribute__((address_space(1))) unsigned int*)g,
            (__attribute__((address_space(3))) unsigned int*)(lds + id * 16),
            16, 0, 0);
    }
}

static __device__ __forceinline__ v8bf frag_read(const char* lds, int ra, int q)
{
    return *(const v8bf*)(lds + ra * 128 + ((q ^ (ra & 7)) << 4));
}

// ---------------------------------------------------------------- k_yn
__global__ __launch_bounds__(256) void k_yn(
    const float* __restrict__ y, const float* __restrict__ Wy,
    const float* __restrict__ by, float* __restrict__ YN)
{
    __shared__ __align__(16) float ysh[DYY];
    int c = blockIdx.x, tid = threadIdx.x;
    for (int i = tid; i < DYY; i += 256) ysh[i] = y[c * DYY + i];
    __syncthreads();
    float acc = by[tid];
    const float4* Wr4 = (const float4*)(Wy + (size_t)tid * DYY);
    const float4* ys4 = (const float4*)ysh;
    for (int d4 = 0; d4 < DYY / 4; ++d4) {
        float4 w = Wr4[d4], yy = ys4[d4];
        acc = fmaf(yy.x, w.x, acc); acc = fmaf(yy.y, w.y, acc);
        acc = fmaf(yy.z, w.z, acc); acc = fmaf(yy.w, w.w, acc);
    }
    YN[c * HH + tid] = 1.0f / (1.0f + __expf(-acc));
}

// ---------------------------------------------------------------- k_proj
// R=32 rows/block. Also zero-inits RS / CM (consumed by k_scores atomics).
__global__ __launch_bounds__(256) void k_proj(
    const float* __restrict__ x0, const float* __restrict__ x1, const float* __restrict__ x2,
    const float* __restrict__ W0, const float* __restrict__ W1, const float* __restrict__ W2,
    const float* __restrict__ b0, const float* __restrict__ b1, const float* __restrict__ b2,
    const int* __restrict__ mask,
    float* __restrict__ XP, __hip_bfloat16* __restrict__ XQh,
    __hip_bfloat16* __restrict__ XPMT,
    float* __restrict__ RS, unsigned int* __restrict__ CM)
{
    const int R = 32;
    int tid = threadIdx.x;
    int blk = blockIdx.x;
    int gt = blk * 256 + tid;
    if (gt < NN) RS[gt] = 0.0f;
    if (gt < NV * NN) CM[gt] = 0u;

    int v  = blk / (NN / R);
    int n0 = (blk % (NN / R)) * R;
    const float* xv = (v == 0) ? x0 : (v == 1 ? x1 : x2);
    const float* Wv = (v == 0) ? W0 : (v == 1 ? W1 : W2);
    const float* bv = (v == 0) ? b0 : (v == 1 ? b1 : b2);

    __shared__ __align__(16) float xsh[R][DD];     // 64 KB
    __shared__ float wred[4][R];
    __shared__ float nrm_sh[R];
    __shared__ int   msk_sh[R];

    const float4* xsrc = (const float4*)(xv + (size_t)n0 * DD);
    for (int i = tid; i < R * DD / 4; i += 256)
        ((float4*)xsh)[i] = xsrc[i];
    if (tid < R) msk_sh[tid] = mask[(n0 + tid) * NV + v];
    __syncthreads();

    float acc[R];
#pragma unroll
    for (int r = 0; r < R; ++r) acc[r] = 0.0f;
    const float4* Wrow = (const float4*)(Wv + (size_t)tid * DD);
#pragma unroll 2
    for (int d4 = 0; d4 < DD / 4; ++d4) {
        float4 w = Wrow[d4];
#pragma unroll
        for (int r = 0; r < R; ++r) {
            acc[r] = fmaf(xsh[r][4 * d4 + 0], w.x, acc[r]);
            acc[r] = fmaf(xsh[r][4 * d4 + 1], w.y, acc[r]);
            acc[r] = fmaf(xsh[r][4 * d4 + 2], w.z, acc[r]);
            acc[r] = fmaf(xsh[r][4 * d4 + 3], w.w, acc[r]);
        }
    }
    float bb = bv[tid];
    float vals[R];
#pragma unroll
    for (int r = 0; r < R; ++r) {
        float t = acc[r] + bb;
        vals[r] = (t >= 0.0f) ? t : 0.1f * t;
    }
    int lane = tid & 63, wv = tid >> 6;
#pragma unroll
    for (int r = 0; r < R; ++r) {
        float sq = vals[r] * vals[r];
#pragma unroll
        for (int off = 32; off > 0; off >>= 1)
            sq += __shfl_down(sq, off, 64);
        if (lane == 0) wred[wv][r] = sq;
    }
    __syncthreads();
    if (tid < R) {
        float s = wred[0][tid] + wred[1][tid] + wred[2][tid] + wred[3][tid];
        nrm_sh[tid] = fmaxf(sqrtf(s), 1e-12f);
    }
    __syncthreads();
#pragma unroll
    for (int r = 0; r < R; ++r) {
        size_t o = ((size_t)v * NN + n0 + r) * HH + tid;
        float xpv = vals[r];
        XP[o]  = xpv;
        XQh[o] = __float2bfloat16(xpv / nrm_sh[r]);
    }
#pragma unroll
    for (int g = 0; g < R / 8; ++g) {
        union { __hip_bfloat16 h[8]; uint4 u; } pk;
#pragma unroll
        for (int r = 0; r < 8; ++r)
            pk.h[r] = __float2bfloat16(msk_sh[g * 8 + r] ? vals[g * 8 + r] : 0.0f);
        *(uint4*)&XPMT[((size_t)v * HH + tid) * NN + n0 + g * 8] = pk.u;
    }
}

// ---------------------------------------------------------------- k_scores
// Full 64x64 grid (4096 blocks, 4 blocks/CU). Wave = one 32x32 MFMA quadrant.
// 2-phase dbuf, 12 K-steps (3 v x 4 k-tiles). Epilogue fuses row-stats:
// shfl-reduce row sums + per-v gated maxes -> LDS -> one global atomic per row.
__global__ __launch_bounds__(256) void k_scores(
    const __hip_bfloat16* __restrict__ XQh, const int* __restrict__ mask,
    __hip_bfloat16* __restrict__ Sb, float* __restrict__ RS,
    unsigned int* __restrict__ CM)
{
    int m0 = blockIdx.x * 64, n0 = blockIdx.y * 64;
    int tid = threadIdx.x, lane = tid & 63, wid = tid >> 6;
    int wr = (wid >> 1) * 32, wc = (wid & 1) * 32;
    int rowA = lane & 31, hi = lane >> 5;

    __shared__ __align__(128) char Ash[2][8192];
    __shared__ __align__(128) char Bsh[2][8192];
    __shared__ int mnsh[NV][64], mmsh[NV][64];
    __shared__ float rsum[64];
    __shared__ unsigned int cmax[NV][64];

    if (tid < 64) {
        rsum[tid] = 0.0f;
#pragma unroll
        for (int v = 0; v < NV; ++v) {
            mnsh[v][tid] = mask[(n0 + tid) * NV + v];
            mmsh[v][tid] = mask[(m0 + tid) * NV + v];
            cmax[v][tid] = 0u;
        }
    }

    float comb[16];
#pragma unroll
    for (int r = 0; r < 16; ++r) comb[r] = -1e30f;
    v16f acc = (v16f)0.0f;

    const __bf16* Abase = (const __bf16*)XQh + (size_t)n0 * HH;
    const __bf16* Bbase = (const __bf16*)XQh + (size_t)m0 * HH;
    const size_t vstep = (size_t)NN * HH;

    stage_tile64(Abase, HH, Ash[0], tid);
    stage_tile64(Bbase, HH, Bsh[0], tid);
    __syncthreads();

    int cur = 0;
#pragma unroll 1
    for (int s = 0; s < 12; ++s) {
        if (s < 11) {
            int sn = s + 1, vn = sn >> 2, kn = (sn & 3) * 64;
            stage_tile64(Abase + (size_t)vn * vstep + kn, HH, Ash[cur ^ 1], tid);
            stage_tile64(Bbase + (size_t)vn * vstep + kn, HH, Bsh[cur ^ 1], tid);
        }
#pragma unroll
        for (int kk = 0; kk < 4; ++kk) {
            int q = kk * 2 + hi;
            v8bf a = frag_read(Ash[cur], wr + rowA, q);
            v8bf b = frag_read(Bsh[cur], wc + rowA, q);
            acc = __builtin_amdgcn_mfma_f32_32x32x16_bf16(a, b, acc, 0, 0, 0);
        }
        if ((s & 3) == 3) {
            int v = s >> 2;
            int cm_ = mmsh[v][wc + rowA];
#pragma unroll
            for (int r = 0; r < 16; ++r) {
                int rown = wr + (r & 3) + 8 * (r >> 2) + 4 * hi;
                float g = (cm_ && mnsh[v][rown]) ? acc[r] : -1e30f;
                comb[r] = fmaxf(comb[r], g);
            }
            acc = (v16f)0.0f;
        }
        __syncthreads();
        cur ^= 1;
    }

    // epilogue: exp + diag-zero + coalesced store
    int col = wc + rowA, m = m0 + col;
    float sv[16];
#pragma unroll
    for (int r = 0; r < 16; ++r) {
        int rown = wr + (r & 3) + 8 * (r >> 2) + 4 * hi;
        float e = __expf(comb[r] * 5.0f);
        if (n0 + rown == m) e = 0.0f;
        sv[r] = e;
        Sb[(size_t)(n0 + rown) * NN + m] = __float2bfloat16(e);
    }

    // fused row sums (shfl within 32-lane halves; hi groups are independent)
#pragma unroll
    for (int r = 0; r < 16; ++r) {
        float x = sv[r];
#pragma unroll
        for (int off = 16; off > 0; off >>= 1)
            x += __shfl_xor(x, off, 64);
        if (rowA == 0) {
            int rown = wr + (r & 3) + 8 * (r >> 2) + 4 * hi;
            atomicAdd(&rsum[rown], x);
        }
    }
    // fused gated maxes per v (S >= 0, so uint compare == float compare)
#pragma unroll
    for (int v = 0; v < NV; ++v) {
        int g = mmsh[v][col];
#pragma unroll
        for (int r = 0; r < 16; ++r) {
            float x = g ? sv[r] : 0.0f;
#pragma unroll
            for (int off = 16; off > 0; off >>= 1)
                x = fmaxf(x, __shfl_xor(x, off, 64));
            if (rowA == 0) {
                int rown = wr + (r & 3) + 8 * (r >> 2) + 4 * hi;
                atomicMax(&cmax[v][rown], __float_as_uint(x));
            }
        }
    }
    __syncthreads();
    if (tid < 64) atomicAdd(&RS[n0 + tid], rsum[tid]);
    if (tid < 64 * NV) {
        int v = tid >> 6, rr = tid & 63;
        atomicMax(&CM[(size_t)v * NN + n0 + rr], cmax[v][rr]);
    }
}

// ---------------------------------------------------------------- k_conf
__global__ __launch_bounds__(256) void k_conf(
    const unsigned int* __restrict__ CM, float* __restrict__ CONF)
{
    int t = blockIdx.x * 256 + threadIdx.x;
    float cm = __uint_as_float(CM[t]);
    float lg = 0.2f * __logf(cm + 1e-9f);
    CONF[t] = fminf(fmaxf(lg, 0.0f), 1.0f);
}

// ---------------------------------------------------------------- k_newx
// 64x64 tiles, grid (NN/64, HH/64, NV) = 768 blocks. Wave = one 32x32 MFMA
// quadrant. 2-phase dbuf, LDS ~33 KB. FUSED: writes Z directly, no k_z.
template<bool FUSED>
__global__ __launch_bounds__(256) void k_newx_t(
    const __hip_bfloat16* __restrict__ Sb, const __hip_bfloat16* __restrict__ XPMT,
    const float* __restrict__ XP, const float* __restrict__ RS,
    const int* __restrict__ mask, const float* __restrict__ YN,
    float* __restrict__ Out)   // FUSED ? Z : NX
{
    int v  = blockIdx.z;
    int n0 = blockIdx.x * 64, h0 = blockIdx.y * 64;
    int tid = threadIdx.x, lane = tid & 63, wid = tid >> 6;
    int wr = (wid >> 1) * 32, wc = (wid & 1) * 32;
    int rowA = lane & 31, hi = lane >> 5;

    __shared__ __align__(128) char Ash[2][8192];
    __shared__ __align__(128) char Bsh[2][8192];
    __shared__ int   mn[64];
    __shared__ float rsn[64];

    if (tid < 64) {
        mn[tid]  = mask[(n0 + tid) * NV + v];
        rsn[tid] = 1.0f / (RS[n0 + tid] + 1e-9f);
    }

    v16f acc = (v16f)0.0f;

    const __bf16* Apanel = (const __bf16*)Sb + (size_t)n0 * NN;
    const __bf16* Bpanel = (const __bf16*)XPMT + ((size_t)v * HH + h0) * NN;

    stage_tile64(Apanel, NN, Ash[0], tid);
    stage_tile64(Bpanel, NN, Bsh[0], tid);
    __syncthreads();

    int cur = 0;
#pragma unroll 1
    for (int t = 0; t < NN / 64; ++t) {
        if (t < NN / 64 - 1) {
            stage_tile64(Apanel + (t + 1) * 64, NN, Ash[cur ^ 1], tid);
            stage_tile64(Bpanel + (t + 1) * 64, NN, Bsh[cur ^ 1], tid);
        }
#pragma unroll
        for (int kk = 0; kk < 4; ++kk) {
            int q = kk * 2 + hi;
            v8bf a = frag_read(Ash[cur], wr + rowA, q);
            v8bf b = frag_read(Bsh[cur], wc + rowA, q);
            acc = __builtin_amdgcn_mfma_f32_32x32x16_bf16(a, b, acc, 0, 0, 0);
        }
        __syncthreads();
        cur ^= 1;
    }

    int h = h0 + wc + rowA;
    float val[16];
#pragma unroll
    for (int r = 0; r < 16; ++r) {
        int rown = wr + (r & 3) + 8 * (r >> 2) + 4 * hi;
        size_t o = ((size_t)v * NN + n0 + rown) * HH + h;
        val[r] = mn[rown] ? XP[o] : acc[r] * rsn[rown];
    }
    if (FUSED) {
        const float* ynp = YN + h;
#pragma unroll 1
        for (int c = 0; c < CC; ++c) {
            float ynv = ynp[c * HH];
#pragma unroll
            for (int r = 0; r < 16; ++r) {
                int rown = wr + (r & 3) + 8 * (r >> 2) + 4 * hi;
                size_t zo = (((size_t)v * NN + n0 + rown) * CC + c) * HH + h;
                Out[zo] = val[r] * ynv;
            }
        }
    } else {
#pragma unroll
        for (int r = 0; r < 16; ++r) {
            int rown = wr + (r & 3) + 8 * (r >> 2) + 4 * hi;
            size_t o = ((size_t)v * NN + n0 + rown) * HH + h;
            Out[o] = val[r];
        }
    }
}

// ---------------------------------------------------------------- k_z (fallback)
__global__ __launch_bounds__(256) void k_z(
    const float* __restrict__ NX, const float* __restrict__ YN,
    float* __restrict__ Z)
{
    int blk = blockIdx.x;
    int tid = threadIdx.x;
    int r = tid >> 6, h4 = (tid & 63) * 4;
    size_t row = (size_t)blk * 4 + r;
    float4 nx = *(const float4*)&NX[row * HH + h4];
    size_t base = row * CC * HH + h4;
#pragma unroll
    for (int c = 0; c < CC; ++c) {
        float4 yn = *(const float4*)&YN[c * HH + h4];
        float4 o;
        o.x = nx.x * yn.x; o.y = nx.y * yn.y;
        o.z = nx.z * yn.z; o.w = nx.w * yn.w;
        *(float4*)&Z[base + (size_t)c * HH] = o;
    }
}

// ---------------------------------------------------------------- launch
extern "C" void kernel_launch(void* const* d_in, const int* in_sizes, int n_in,
                              void* d_out, int out_size, void* d_ws, size_t ws_size,
                              hipStream_t stream)
{
    (void)in_sizes; (void)n_in; (void)out_size;
    const float* x0 = (const float*)d_in[0];
    const float* W0 = (const float*)d_in[1];
    const float* b0 = (const float*)d_in[2];
    const float* x1 = (const float*)d_in[3];
    const float* W1 = (const float*)d_in[4];
    const float* b1 = (const float*)d_in[5];
    const float* x2 = (const float*)d_in[6];
    const float* W2 = (const float*)d_in[7];
    const float* b2 = (const float*)d_in[8];
    const float* y  = (const float*)d_in[9];
    const float* Wy = (const float*)d_in[10];
    const float* by = (const float*)d_in[11];
    const int* mask = (const int*)d_in[12];
    float* out = (float*)d_out;
    float* CONF = out + (size_t)NV * NN * CC * HH;

    // Fused-path ws layout (bytes):
    //   Sb   bf16 NN*NN   @ 0          33,554,432
    //   XPMT bf16 V*H*N   @ 33554432    6,291,456
    //   XQh  bf16 V*N*H   @ 39845888    6,291,456
    //   XP   f32  V*N*H   @ 46137344   12,582,912
    //   RS   f32  N       @ 58720256       16,384
    //   YN   f32  C*H     @ 58736640       81,920
    //   CM   u32  V*N     @ 58818560       49,152
    const size_t WS_NEED = 58867712u;

    if (ws_size >= WS_NEED) {
        char* w = (char*)d_ws;
        __hip_bfloat16* Sb   = (__hip_bfloat16*)w;
        __hip_bfloat16* XPMT = (__hip_bfloat16*)(w + 33554432);
        __hip_bfloat16* XQh  = (__hip_bfloat16*)(w + 39845888);
        float*          XP   = (float*)(w + 46137344);
        float*          RS   = (float*)(w + 58720256);
        float*          YN   = (float*)(w + 58736640);
        unsigned int*   CM   = (unsigned int*)(w + 58818560);

        k_yn<<<CC, 256, 0, stream>>>(y, Wy, by, YN);
        k_proj<<<NV * NN / 32, 256, 0, stream>>>(x0, x1, x2, W0, W1, W2,
                                                 b0, b1, b2, mask, XP, XQh, XPMT,
                                                 RS, CM);
        dim3 gs(NN / 64, NN / 64);
        k_scores<<<gs, 256, 0, stream>>>(XQh, mask, Sb, RS, CM);
        k_conf<<<NV * NN / 256, 256, 0, stream>>>(CM, CONF);
        dim3 gn(NN / 64, HH / 64, NV);
        k_newx_t<true><<<gn, 256, 0, stream>>>(Sb, XPMT, XP, RS, mask, YN, out);
    } else {
        // Fallback: scratch carved from out's Z region (dead until k_z),
        // NX/RS/YN/CM in ws (~12.73 MB).
        __hip_bfloat16* Sb   = (__hip_bfloat16*)out;
        float*          XP   = out + 8388608;
        __hip_bfloat16* XQh  = (__hip_bfloat16*)(out + 11534336);
        __hip_bfloat16* XPMT = (__hip_bfloat16*)(out + 13107200);
        char* w = (char*)d_ws;
        float*        NX = (float*)w;
        float*        RS = (float*)(w + 12582912);
        float*        YN = (float*)(w + 12599296);
        unsigned int* CM = (unsigned int*)(w + 12681216);

        k_yn<<<CC, 256, 0, stream>>>(y, Wy, by, YN);
        k_proj<<<NV * NN / 32, 256, 0, stream>>>(x0, x1, x2, W0, W1, W2,
                                                 b0, b1, b2, mask, XP, XQh, XPMT,
                                                 RS, CM);
        dim3 gs(NN / 64, NN / 64);
        k_scores<<<gs, 256, 0, stream>>>(XQh, mask, Sb, RS, CM);
        k_conf<<<NV * NN / 256, 256, 0, stream>>>(CM, CONF);
        dim3 gn(NN / 64, HH / 64, NV);
        k_newx_t<false><<<gn, 256, 0, stream>>>(Sb, XPMT, XP, RS, mask, YN, NX);
        k_z<<<NV * NN / 4, 256, 0, stream>>>(NX, YN, out);
    }
}